// Round 1
// baseline (1612.620 us; speedup 1.0000x reference)
//
#include <hip/hip_runtime.h>
#include <hip/hip_bf16.h>

#define N_NODES 40000
#define N_EDGES 320000
#define DIM 128
#define HC 512
#define NHEAD 4
#define CHEAD 128
#define DEPTH_L 2
#define MLP_DIM 512

static __device__ __forceinline__ float toF(float v) { return v; }
static __device__ __forceinline__ float toF(__hip_bfloat16 v) { return __bfloat162float(v); }

// ---------------- LayerNorm: one wave per row (D=128, 2 elems/lane) ----------
__global__ __launch_bounds__(256) void k_ln(const float* __restrict__ x,
                                            const float* __restrict__ gma,
                                            const float* __restrict__ bta,
                                            float* __restrict__ out, int M)
{
    int row = blockIdx.x * 4 + (threadIdx.x >> 6);
    int lane = threadIdx.x & 63;
    if (row >= M) return;
    float2 v = *reinterpret_cast<const float2*>(x + (size_t)row * DIM + lane * 2);
    float s = v.x + v.y, sq = v.x * v.x + v.y * v.y;
    #pragma unroll
    for (int d = 32; d; d >>= 1) { s += __shfl_xor(s, d); sq += __shfl_xor(sq, d); }
    float mean = s * (1.f / DIM);
    float var = sq * (1.f / DIM) - mean * mean;
    float rs = rsqrtf(var + 1e-5f);
    int c = lane * 2;
    float2 o;
    o.x = (v.x - mean) * rs * gma[c] + bta[c];
    o.y = (v.y - mean) * rs * gma[c + 1] + bta[c + 1];
    *reinterpret_cast<float2*>(out + (size_t)row * DIM + c) = o;
}

// ---------------- fp32 tiled GEMM: C[M,N] = A[M,K] @ B[K,N] (+bias)(+gelu)(+resid)
// BM=BN=128, BK=16, 256 threads, 8x8 microtile.
template <typename TA, bool GELU, bool RESID>
__global__ __launch_bounds__(256) void k_gemm(const TA* __restrict__ A,
                                              const float* __restrict__ B,
                                              const float* __restrict__ bias,
                                              const float* __restrict__ resid,
                                              void* __restrict__ Cout,
                                              int M, int N, int K)
{
    const int BM = 128, BN = 128, BK = 16;
    __shared__ float As[BK][BM + 4];
    __shared__ float Bs[BK][BN + 4];
    int tx = threadIdx.x & 15, ty = threadIdx.x >> 4;
    int m0 = blockIdx.x * BM, n0 = blockIdx.y * BN;
    float acc[8][8] = {};
    for (int k0 = 0; k0 < K; k0 += BK) {
        for (int i = threadIdx.x; i < BM * BK; i += 256) {
            int r = i / BK, c = i % BK;
            float v = (m0 + r < M) ? toF(A[(size_t)(m0 + r) * K + k0 + c]) : 0.f;
            As[c][r] = v;
        }
        for (int i = threadIdx.x; i < BK * BN; i += 256) {
            int r = i / BN, c = i % BN;
            Bs[r][c] = B[(size_t)(k0 + r) * N + n0 + c];
        }
        __syncthreads();
        #pragma unroll
        for (int kk = 0; kk < BK; kk++) {
            float a[8], b[8];
            #pragma unroll
            for (int i = 0; i < 8; i++) a[i] = As[kk][ty * 8 + i];
            #pragma unroll
            for (int j = 0; j < 8; j++) b[j] = Bs[kk][tx * 8 + j];
            #pragma unroll
            for (int i = 0; i < 8; i++)
                #pragma unroll
                for (int j = 0; j < 8; j++) acc[i][j] += a[i] * b[j];
        }
        __syncthreads();
    }
    #pragma unroll
    for (int i = 0; i < 8; i++) {
        int m = m0 + ty * 8 + i;
        if (m >= M) continue;
        #pragma unroll
        for (int j = 0; j < 8; j++) {
            int n = n0 + tx * 8 + j;
            float v = acc[i][j];
            if (bias) v += bias[n];
            if (GELU) {
                float u = v;
                v = 0.5f * u * (1.f + tanhf(0.7978845608f * (u + 0.044715f * u * u * u)));
            }
            if (RESID) {
                ((float*)Cout)[(size_t)m * N + n] = resid[(size_t)m * N + n] + v;
            } else {
                ((__hip_bfloat16*)Cout)[(size_t)m * N + n] = __float2bfloat16(v);
            }
        }
    }
}

// ---------------- per-(node,head) dots with att_src/att_dst: one wave each ----
__global__ __launch_bounds__(256) void k_nodedots(const __hip_bfloat16* __restrict__ h2,
                                                  const float* __restrict__ a_src,
                                                  const float* __restrict__ a_dst,
                                                  float* __restrict__ asrc,
                                                  float* __restrict__ adst)
{
    int idx = blockIdx.x * 4 + (threadIdx.x >> 6);  // (n,h)
    int lane = threadIdx.x & 63;
    int n = idx >> 2, h = idx & 3;
    if (n >= N_NODES) return;
    unsigned int u = *reinterpret_cast<const unsigned int*>(h2 + (size_t)n * HC + h * CHEAD + lane * 2);
    float f0 = __uint_as_float(u << 16);
    float f1 = __uint_as_float(u & 0xffff0000u);
    float2 as = *reinterpret_cast<const float2*>(a_src + h * CHEAD + lane * 2);
    float2 ad = *reinterpret_cast<const float2*>(a_dst + h * CHEAD + lane * 2);
    float s1 = f0 * as.x + f1 * as.y;
    float s2 = f0 * ad.x + f1 * ad.y;
    #pragma unroll
    for (int d = 32; d; d >>= 1) { s1 += __shfl_xor(s1, d); s2 += __shfl_xor(s2, d); }
    if (lane == 0) { asrc[idx] = s1; adst[idx] = s2; }
}

// ---------------- per-head edge scalar: ae[h] = dot(We[h,:], a_edge[h,:]) -----
__global__ void k_ae(const float* __restrict__ We, const float* __restrict__ a_edge,
                     float* __restrict__ ae)
{
    int h = threadIdx.x >> 6, lane = threadIdx.x & 63;
    float2 w = *reinterpret_cast<const float2*>(We + h * CHEAD + lane * 2);
    float2 a = *reinterpret_cast<const float2*>(a_edge + h * CHEAD + lane * 2);
    float s = w.x * a.x + w.y * a.y;
    #pragma unroll
    for (int d = 32; d; d >>= 1) s += __shfl_xor(s, d);
    if (lane == 0) ae[h] = s;
}

// ---------------- CSR build ---------------------------------------------------
__global__ void k_hist(const int* __restrict__ dst, int* __restrict__ deg)
{
    int e = blockIdx.x * 256 + threadIdx.x;
    if (e < N_EDGES) atomicAdd(&deg[dst[e]], 1);
}

__global__ __launch_bounds__(1024) void k_scan(const int* __restrict__ deg,
                                               int* __restrict__ off, int n)
{
    __shared__ int wsum[16];
    __shared__ int carry;
    int t = threadIdx.x, lane = t & 63, w = t >> 6;
    if (t == 0) carry = 0;
    __syncthreads();
    for (int base = 0; base < n; base += 1024) {
        int i = base + t;
        int v = (i < n) ? deg[i] : 0;
        int s = v;
        #pragma unroll
        for (int d = 1; d < 64; d <<= 1) {
            int u = __shfl_up(s, d);
            if (lane >= d) s += u;
        }
        if (lane == 63) wsum[w] = s;
        __syncthreads();
        int wpre = 0;
        for (int j = 0; j < w; j++) wpre += wsum[j];
        int c0 = carry;
        if (i < n) off[i] = c0 + wpre + s - v;
        __syncthreads();
        if (t == 1023) carry = c0 + wpre + s;
        __syncthreads();
    }
    if (t == 0) off[n] = carry;
}

__global__ void k_cursor(const int* __restrict__ off, int* __restrict__ cur)
{
    int n = blockIdx.x * 256 + threadIdx.x;
    if (n < N_NODES) cur[n] = off[n];
}

__global__ void k_fill(const int* __restrict__ dst, int* __restrict__ cur,
                       int* __restrict__ elist)
{
    int e = blockIdx.x * 256 + threadIdx.x;
    if (e < N_EDGES) {
        int p = atomicAdd(&cur[dst[e]], 1);
        elist[p] = e;
    }
}

// ---------------- fused segment softmax + aggregate: 1 wave per node ----------
// out[n,h,c] = (sum_e w_e * h2[src_e,h,c]) / (sum_e w_e + eps) + bias
__global__ __launch_bounds__(64) void k_agg(const int* __restrict__ off,
                                            const int* __restrict__ elist,
                                            const int* __restrict__ src,
                                            const float* __restrict__ ea,
                                            const float* __restrict__ asrc,
                                            const float* __restrict__ adst,
                                            const float* __restrict__ ae4,
                                            const __hip_bfloat16* __restrict__ h2,
                                            const float* __restrict__ bias,
                                            __hip_bfloat16* __restrict__ g)
{
    int n = blockIdx.x;
    int t = threadIdx.x;
    int h = t >> 4;        // 16 threads per head
    int cb = t * 8;        // 8 channels per thread, = h*128 + (t%16)*8
    int e0 = off[n], e1 = off[n + 1];
    float adh = adst[n * 4 + h];
    float aeh = ae4[h];
    float m = -INFINITY;
    for (int i = e0; i < e1; i++) {
        int e = elist[i];
        int s_ = src[e];
        float al = asrc[s_ * 4 + h] + adh + aeh * ea[e];
        al = al > 0.f ? al : 0.2f * al;
        m = fmaxf(m, al);
    }
    float den = 0.f;
    float acc[8] = {0, 0, 0, 0, 0, 0, 0, 0};
    for (int i = e0; i < e1; i++) {
        int e = elist[i];
        int s_ = src[e];
        float al = asrc[s_ * 4 + h] + adh + aeh * ea[e];
        al = al > 0.f ? al : 0.2f * al;
        float wgt = __expf(al - m);
        den += wgt;
        uint4 v = *reinterpret_cast<const uint4*>(h2 + (size_t)s_ * HC + cb);
        float f[8];
        f[0] = __uint_as_float(v.x << 16); f[1] = __uint_as_float(v.x & 0xffff0000u);
        f[2] = __uint_as_float(v.y << 16); f[3] = __uint_as_float(v.y & 0xffff0000u);
        f[4] = __uint_as_float(v.z << 16); f[5] = __uint_as_float(v.z & 0xffff0000u);
        f[6] = __uint_as_float(v.w << 16); f[7] = __uint_as_float(v.w & 0xffff0000u);
        #pragma unroll
        for (int j = 0; j < 8; j++) acc[j] += wgt * f[j];
    }
    float sc = 1.f / (den + 1e-16f);
    union { uint4 u; __hip_bfloat16 b[8]; } o;
    #pragma unroll
    for (int j = 0; j < 8; j++) o.b[j] = __float2bfloat16(acc[j] * sc + bias[cb + j]);
    *reinterpret_cast<uint4*>(g + (size_t)n * HC + cb) = o.u;
}

extern "C" void kernel_launch(void* const* d_in, const int* in_sizes, int n_in,
                              void* d_out, int out_size, void* d_ws, size_t ws_size,
                              hipStream_t stream)
{
    const float* x_in     = (const float*)d_in[0];
    const int*   ei       = (const int*)d_in[1];
    const float* ea       = (const float*)d_in[2];
    const float* ln1_g    = (const float*)d_in[3];
    const float* ln1_b    = (const float*)d_in[4];
    const float* gat_W    = (const float*)d_in[5];
    const float* att_src  = (const float*)d_in[6];
    const float* att_dst  = (const float*)d_in[7];
    const float* edge_W   = (const float*)d_in[8];
    const float* att_edge = (const float*)d_in[9];
    const float* gat_bias = (const float*)d_in[10];
    const float* qf_W     = (const float*)d_in[11];
    const float* qf_b     = (const float*)d_in[12];
    const float* ln2_g    = (const float*)d_in[13];
    const float* ln2_b    = (const float*)d_in[14];
    const float* ff_W1    = (const float*)d_in[15];
    const float* ff_b1    = (const float*)d_in[16];
    const float* ff_W2    = (const float*)d_in[17];
    const float* ff_b2    = (const float*)d_in[18];
    float* x = (float*)d_out;

    char* ws = (char*)d_ws;
    size_t o = 0;
    auto alloc = [&](size_t b) { size_t r = o; o += (b + 255) & ~(size_t)255; return r; };
    float*           h_ln  = (float*)(ws + alloc((size_t)N_NODES * DIM * 4));
    __hip_bfloat16*  h2    = (__hip_bfloat16*)(ws + alloc((size_t)N_NODES * HC * 2));
    __hip_bfloat16*  gbuf  = (__hip_bfloat16*)(ws + alloc((size_t)N_NODES * HC * 2));
    float*           asrc  = (float*)(ws + alloc((size_t)N_NODES * 4 * 4));
    float*           adst  = (float*)(ws + alloc((size_t)N_NODES * 4 * 4));
    float*           ae4   = (float*)(ws + alloc(256));
    int*             deg   = (int*)(ws + alloc((size_t)(N_NODES + 1) * 4));
    int*             off   = (int*)(ws + alloc((size_t)(N_NODES + 1) * 4));
    int*             cur   = (int*)(ws + alloc((size_t)N_NODES * 4));
    int*             elist = (int*)(ws + alloc((size_t)N_EDGES * 4));

    const int* srcA = ei;
    const int* dstA = ei + N_EDGES;

    hipMemcpyAsync(x, x_in, (size_t)N_NODES * DIM * 4, hipMemcpyDeviceToDevice, stream);

    // CSR by dst (edges identical across layers)
    hipMemsetAsync(deg, 0, (size_t)(N_NODES + 1) * 4, stream);
    k_hist<<<(N_EDGES + 255) / 256, 256, 0, stream>>>(dstA, deg);
    k_scan<<<1, 1024, 0, stream>>>(deg, off, N_NODES);
    k_cursor<<<(N_NODES + 255) / 256, 256, 0, stream>>>(off, cur);
    k_fill<<<(N_EDGES + 255) / 256, 256, 0, stream>>>(dstA, cur, elist);

    const int MB = (N_NODES + 127) / 128;  // 313
    for (int d = 0; d < DEPTH_L; ++d) {
        // PreNorm + GAT
        k_ln<<<N_NODES / 4, 256, 0, stream>>>(x, ln1_g + d * DIM, ln1_b + d * DIM, h_ln, N_NODES);
        dim3 g1(MB, HC / 128);
        k_gemm<float, false, false><<<g1, 256, 0, stream>>>(
            h_ln, gat_W + (size_t)d * DIM * HC, nullptr, nullptr, h2, N_NODES, HC, DIM);
        k_nodedots<<<N_NODES, 256, 0, stream>>>(
            h2, att_src + d * NHEAD * CHEAD, att_dst + d * NHEAD * CHEAD, asrc, adst);
        k_ae<<<1, 256, 0, stream>>>(edge_W + d * HC, att_edge + d * NHEAD * CHEAD, ae4);
        k_agg<<<N_NODES, 64, 0, stream>>>(off, elist, srcA, ea, asrc, adst, ae4, h2,
                                          gat_bias + d * HC, gbuf);
        dim3 g2(MB, 1);
        k_gemm<__hip_bfloat16, false, true><<<g2, 256, 0, stream>>>(
            gbuf, qf_W + (size_t)d * HC * DIM, qf_b + d * DIM, x, x, N_NODES, DIM, HC);
        // PreNorm + FF
        k_ln<<<N_NODES / 4, 256, 0, stream>>>(x, ln2_g + d * DIM, ln2_b + d * DIM, h_ln, N_NODES);
        k_gemm<float, true, false><<<g1, 256, 0, stream>>>(
            h_ln, ff_W1 + (size_t)d * DIM * MLP_DIM, ff_b1 + d * MLP_DIM, nullptr, gbuf,
            N_NODES, MLP_DIM, DIM);
        k_gemm<__hip_bfloat16, false, true><<<g2, 256, 0, stream>>>(
            gbuf, ff_W2 + (size_t)d * MLP_DIM * DIM, ff_b2 + d * DIM, x, x, N_NODES, DIM, MLP_DIM);
    }
}

// Round 2
// 593.805 us; speedup vs baseline: 2.7157x; 2.7157x over previous
//
#include <hip/hip_runtime.h>
#include <hip/hip_bf16.h>

#define N_NODES 40000
#define M_PAD   40064            // padded row count for A-operand staging
#define N_EDGES 320000
#define DIM 128
#define HC 512
#define NHEAD 4
#define CHEAD 128
#define DEPTH_L 2
#define MLP_DIM 512

typedef __attribute__((ext_vector_type(8))) short short8;   // 8 bf16 = 4 VGPR
typedef __attribute__((ext_vector_type(4))) float f32x4;

static __device__ __forceinline__ void gload_lds16(const void* g, void* l)
{
    __builtin_amdgcn_global_load_lds(
        (const __attribute__((address_space(1))) unsigned int*)g,
        (__attribute__((address_space(3))) unsigned int*)l,
        16, 0, 0);
}

// ---------------- LayerNorm: one wave per row, bf16 output -------------------
__global__ __launch_bounds__(256) void k_ln(const float* __restrict__ x,
                                            const float* __restrict__ gma,
                                            const float* __restrict__ bta,
                                            __hip_bfloat16* __restrict__ out, int M)
{
    int row = blockIdx.x * 4 + (threadIdx.x >> 6);
    int lane = threadIdx.x & 63;
    if (row >= M) return;
    float2 v = *reinterpret_cast<const float2*>(x + (size_t)row * DIM + lane * 2);
    float s = v.x + v.y, sq = v.x * v.x + v.y * v.y;
    #pragma unroll
    for (int d = 32; d; d >>= 1) { s += __shfl_xor(s, d); sq += __shfl_xor(sq, d); }
    float mean = s * (1.f / DIM);
    float var = sq * (1.f / DIM) - mean * mean;
    float rs = rsqrtf(var + 1e-5f);
    int c = lane * 2;
    union { __hip_bfloat16 b[2]; unsigned int u; } p;
    p.b[0] = __float2bfloat16((v.x - mean) * rs * gma[c] + bta[c]);
    p.b[1] = __float2bfloat16((v.y - mean) * rs * gma[c + 1] + bta[c + 1]);
    *reinterpret_cast<unsigned int*>(out + (size_t)row * DIM + c) = p.u;
}

// ---------------- weight convert + transpose: W[K][N] f32 -> Wt[N][K] bf16 ---
__global__ __launch_bounds__(256) void k_wcvt(const float* __restrict__ W,
                                              __hip_bfloat16* __restrict__ Wt,
                                              int K, int N)
{
    int i = blockIdx.x * 256 + threadIdx.x;     // index into Wt (N*K)
    if (i < K * N) {
        int n = i / K, k = i % K;
        Wt[i] = __float2bfloat16(W[(size_t)k * N + n]);
    }
}

// ---------------- bf16 MFMA GEMM: C[M,N] = A[M,K] @ Bt[N,K]^T ----------------
// 128x128 tile, BK=64, 4 waves (each 64x64 = 4x4 frags of 16x16x32).
// LDS tiles [128 rows][64 cols bf16], XOR-swizzled 16B chunks (slot = g ^ (r&7)),
// staged via global_load_lds w=16 with inverse-swizzled global source.
// MODE: 0 = bf16 out (no bias)   1 = bf16 out, bias+gelu   2 = f32 out, bias+resid
template <int MODE>
__global__ __launch_bounds__(256) void k_mm(const short* __restrict__ A,
                                            const short* __restrict__ Bt,
                                            const float* __restrict__ bias,
                                            const float* __restrict__ resid,
                                            void* __restrict__ Cout,
                                            int M, int N, int K)
{
    __shared__ __align__(16) short Als[128 * 64];
    __shared__ __align__(16) short Bls[128 * 64];
    const int tid = threadIdx.x;
    const int lane = tid & 63;
    const int w = tid >> 6;
    const int wr = w >> 1, wc = w & 1;
    const int lrow = lane & 15;
    const int lk = lane >> 4;
    const int m0 = blockIdx.x * 128;
    const int n0 = blockIdx.y * 128;

    f32x4 acc[4][4] = {};

    for (int kt = 0; kt < K; kt += 64) {
        // stage: each wave issues 4x A + 4x B global_load_lds (1 KB each)
        #pragma unroll
        for (int q = 0; q < 4; ++q) {
            int c = (w * 4 + q) * 64 + lane;        // chunk id 0..1023
            int r = c >> 3, g = c & 7;
            int gp = g ^ (r & 7);                    // inverse-swizzled source
            gload_lds16(A + (size_t)(m0 + r) * K + kt + gp * 8,
                        &Als[(w * 4 + q) * 512]);
            gload_lds16(Bt + (size_t)(n0 + r) * K + kt + gp * 8,
                        &Bls[(w * 4 + q) * 512]);
        }
        __syncthreads();   // drains vmcnt(0)

        #pragma unroll
        for (int ks = 0; ks < 2; ++ks) {
            short8 af[4], bf[4];
            #pragma unroll
            for (int fi = 0; fi < 4; ++fi) {
                int r = wr * 64 + fi * 16 + lrow;
                int g = ks * 4 + lk;
                af[fi] = *reinterpret_cast<const short8*>(&Als[r * 64 + (g ^ (r & 7)) * 8]);
            }
            #pragma unroll
            for (int fj = 0; fj < 4; ++fj) {
                int r = wc * 64 + fj * 16 + lrow;
                int g = ks * 4 + lk;
                bf[fj] = *reinterpret_cast<const short8*>(&Bls[r * 64 + (g ^ (r & 7)) * 8]);
            }
            #pragma unroll
            for (int fi = 0; fi < 4; ++fi)
                #pragma unroll
                for (int fj = 0; fj < 4; ++fj)
                    acc[fi][fj] = __builtin_amdgcn_mfma_f32_16x16x32_bf16(
                        af[fi], bf[fj], acc[fi][fj], 0, 0, 0);
        }
        __syncthreads();
    }

    // epilogue: C/D layout col = lane&15, row = (lane>>4)*4 + p
    #pragma unroll
    for (int fi = 0; fi < 4; ++fi) {
        #pragma unroll
        for (int fj = 0; fj < 4; ++fj) {
            #pragma unroll
            for (int p = 0; p < 4; ++p) {
                int m = m0 + wr * 64 + fi * 16 + lk * 4 + p;
                int n = n0 + wc * 64 + fj * 16 + lrow;
                if (m >= M) continue;
                float v = acc[fi][fj][p];
                if (MODE == 0) {
                    ((__hip_bfloat16*)Cout)[(size_t)m * N + n] = __float2bfloat16(v);
                } else if (MODE == 1) {
                    v += bias[n];
                    float u = v;
                    v = 0.5f * u * (1.f + tanhf(0.7978845608f * (u + 0.044715f * u * u * u)));
                    ((__hip_bfloat16*)Cout)[(size_t)m * N + n] = __float2bfloat16(v);
                } else {
                    v += bias[n] + resid[(size_t)m * N + n];
                    ((float*)Cout)[(size_t)m * N + n] = v;
                }
            }
        }
    }
}

// ---------------- per-(node,head) dots with att_src/att_dst ------------------
__global__ __launch_bounds__(256) void k_nodedots(const __hip_bfloat16* __restrict__ h2,
                                                  const float* __restrict__ a_src,
                                                  const float* __restrict__ a_dst,
                                                  float* __restrict__ asrc,
                                                  float* __restrict__ adst)
{
    int idx = blockIdx.x * 4 + (threadIdx.x >> 6);  // (n,h)
    int lane = threadIdx.x & 63;
    int n = idx >> 2, h = idx & 3;
    if (n >= N_NODES) return;
    unsigned int u = *reinterpret_cast<const unsigned int*>(h2 + (size_t)n * HC + h * CHEAD + lane * 2);
    float f0 = __uint_as_float(u << 16);
    float f1 = __uint_as_float(u & 0xffff0000u);
    float2 as = *reinterpret_cast<const float2*>(a_src + h * CHEAD + lane * 2);
    float2 ad = *reinterpret_cast<const float2*>(a_dst + h * CHEAD + lane * 2);
    float s1 = f0 * as.x + f1 * as.y;
    float s2 = f0 * ad.x + f1 * ad.y;
    #pragma unroll
    for (int d = 32; d; d >>= 1) { s1 += __shfl_xor(s1, d); s2 += __shfl_xor(s2, d); }
    if (lane == 0) { asrc[idx] = s1; adst[idx] = s2; }
}

__global__ void k_ae(const float* __restrict__ We, const float* __restrict__ a_edge,
                     float* __restrict__ ae)
{
    int h = threadIdx.x >> 6, lane = threadIdx.x & 63;
    float2 w = *reinterpret_cast<const float2*>(We + h * CHEAD + lane * 2);
    float2 a = *reinterpret_cast<const float2*>(a_edge + h * CHEAD + lane * 2);
    float s = w.x * a.x + w.y * a.y;
    #pragma unroll
    for (int d = 32; d; d >>= 1) s += __shfl_xor(s, d);
    if (lane == 0) ae[h] = s;
}

// ---------------- CSR build ---------------------------------------------------
__global__ void k_hist(const int* __restrict__ dst, int* __restrict__ deg)
{
    int e = blockIdx.x * 256 + threadIdx.x;
    if (e < N_EDGES) atomicAdd(&deg[dst[e]], 1);
}

__global__ __launch_bounds__(1024) void k_scan(const int* __restrict__ deg,
                                               int* __restrict__ off, int n)
{
    __shared__ int wsum[16];
    __shared__ int carry;
    int t = threadIdx.x, lane = t & 63, w = t >> 6;
    if (t == 0) carry = 0;
    __syncthreads();
    for (int base = 0; base < n; base += 1024) {
        int i = base + t;
        int v = (i < n) ? deg[i] : 0;
        int s = v;
        #pragma unroll
        for (int d = 1; d < 64; d <<= 1) {
            int u = __shfl_up(s, d);
            if (lane >= d) s += u;
        }
        if (lane == 63) wsum[w] = s;
        __syncthreads();
        int wpre = 0;
        for (int j = 0; j < w; j++) wpre += wsum[j];
        int c0 = carry;
        if (i < n) off[i] = c0 + wpre + s - v;
        __syncthreads();
        if (t == 1023) carry = c0 + wpre + s;
        __syncthreads();
    }
    if (t == 0) off[n] = carry;
}

__global__ void k_cursor(const int* __restrict__ off, int* __restrict__ cur)
{
    int n = blockIdx.x * 256 + threadIdx.x;
    if (n < N_NODES) cur[n] = off[n];
}

__global__ void k_fill(const int* __restrict__ dst, int* __restrict__ cur,
                       int* __restrict__ elist)
{
    int e = blockIdx.x * 256 + threadIdx.x;
    if (e < N_EDGES) {
        int p = atomicAdd(&cur[dst[e]], 1);
        elist[p] = e;
    }
}

// ---------------- fused segment softmax + aggregate: 1 wave per node ----------
__global__ __launch_bounds__(64) void k_agg(const int* __restrict__ off,
                                            const int* __restrict__ elist,
                                            const int* __restrict__ src,
                                            const float* __restrict__ ea,
                                            const float* __restrict__ asrc,
                                            const float* __restrict__ adst,
                                            const float* __restrict__ ae4,
                                            const __hip_bfloat16* __restrict__ h2,
                                            const float* __restrict__ bias,
                                            __hip_bfloat16* __restrict__ g)
{
    int n = blockIdx.x;
    int t = threadIdx.x;
    int h = t >> 4;
    int cb = t * 8;
    int e0 = off[n], e1 = off[n + 1];
    float adh = adst[n * 4 + h];
    float aeh = ae4[h];
    float m = -INFINITY;
    for (int i = e0; i < e1; i++) {
        int e = elist[i];
        int s_ = src[e];
        float al = asrc[s_ * 4 + h] + adh + aeh * ea[e];
        al = al > 0.f ? al : 0.2f * al;
        m = fmaxf(m, al);
    }
    float den = 0.f;
    float acc[8] = {0, 0, 0, 0, 0, 0, 0, 0};
    for (int i = e0; i < e1; i++) {
        int e = elist[i];
        int s_ = src[e];
        float al = asrc[s_ * 4 + h] + adh + aeh * ea[e];
        al = al > 0.f ? al : 0.2f * al;
        float wgt = __expf(al - m);
        den += wgt;
        uint4 v = *reinterpret_cast<const uint4*>(h2 + (size_t)s_ * HC + cb);
        float f[8];
        f[0] = __uint_as_float(v.x << 16); f[1] = __uint_as_float(v.x & 0xffff0000u);
        f[2] = __uint_as_float(v.y << 16); f[3] = __uint_as_float(v.y & 0xffff0000u);
        f[4] = __uint_as_float(v.z << 16); f[5] = __uint_as_float(v.z & 0xffff0000u);
        f[6] = __uint_as_float(v.w << 16); f[7] = __uint_as_float(v.w & 0xffff0000u);
        #pragma unroll
        for (int j = 0; j < 8; j++) acc[j] += wgt * f[j];
    }
    float sc = 1.f / (den + 1e-16f);
    union { uint4 u; __hip_bfloat16 b[8]; } o;
    #pragma unroll
    for (int j = 0; j < 8; j++) o.b[j] = __float2bfloat16(acc[j] * sc + bias[cb + j]);
    *reinterpret_cast<uint4*>(g + (size_t)n * HC + cb) = o.u;
}

extern "C" void kernel_launch(void* const* d_in, const int* in_sizes, int n_in,
                              void* d_out, int out_size, void* d_ws, size_t ws_size,
                              hipStream_t stream)
{
    const float* x_in     = (const float*)d_in[0];
    const int*   ei       = (const int*)d_in[1];
    const float* ea       = (const float*)d_in[2];
    const float* ln1_g    = (const float*)d_in[3];
    const float* ln1_b    = (const float*)d_in[4];
    const float* gat_W    = (const float*)d_in[5];
    const float* att_src  = (const float*)d_in[6];
    const float* att_dst  = (const float*)d_in[7];
    const float* edge_W   = (const float*)d_in[8];
    const float* att_edge = (const float*)d_in[9];
    const float* gat_bias = (const float*)d_in[10];
    const float* qf_W     = (const float*)d_in[11];
    const float* qf_b     = (const float*)d_in[12];
    const float* ln2_g    = (const float*)d_in[13];
    const float* ln2_b    = (const float*)d_in[14];
    const float* ff_W1    = (const float*)d_in[15];
    const float* ff_b1    = (const float*)d_in[16];
    const float* ff_W2    = (const float*)d_in[17];
    const float* ff_b2    = (const float*)d_in[18];
    float* x = (float*)d_out;

    char* ws = (char*)d_ws;
    size_t o = 0;
    auto alloc = [&](size_t b) { size_t r = o; o += (b + 255) & ~(size_t)255; return r; };
    __hip_bfloat16*  h_ln  = (__hip_bfloat16*)(ws + alloc((size_t)M_PAD * DIM * 2));
    __hip_bfloat16*  h2    = (__hip_bfloat16*)(ws + alloc((size_t)N_NODES * HC * 2));
    __hip_bfloat16*  gbuf  = (__hip_bfloat16*)(ws + alloc((size_t)M_PAD * HC * 2));
    float*           asrc  = (float*)(ws + alloc((size_t)N_NODES * 4 * 4));
    float*           adst  = (float*)(ws + alloc((size_t)N_NODES * 4 * 4));
    float*           ae4   = (float*)(ws + alloc(256));
    int*             deg   = (int*)(ws + alloc((size_t)(N_NODES + 1) * 4));
    int*             off   = (int*)(ws + alloc((size_t)(N_NODES + 1) * 4));
    int*             cur   = (int*)(ws + alloc((size_t)N_NODES * 4));
    int*             elist = (int*)(ws + alloc((size_t)N_EDGES * 4));
    // bf16 transposed weights, per layer: gat_Wt, qf_Wt, ff_W1t, ff_W2t
    __hip_bfloat16* Wt[DEPTH_L][4];
    for (int d = 0; d < DEPTH_L; ++d)
        for (int j = 0; j < 4; ++j)
            Wt[d][j] = (__hip_bfloat16*)(ws + alloc((size_t)65536 * 2));

    const int* srcA = ei;
    const int* dstA = ei + N_EDGES;

    hipMemcpyAsync(x, x_in, (size_t)N_NODES * DIM * 4, hipMemcpyDeviceToDevice, stream);

    // weight convert+transpose (all layers, once)
    for (int d = 0; d < DEPTH_L; ++d) {
        k_wcvt<<<256, 256, 0, stream>>>(gat_W + (size_t)d * DIM * HC,  Wt[d][0], DIM, HC);
        k_wcvt<<<256, 256, 0, stream>>>(qf_W  + (size_t)d * HC * DIM,  Wt[d][1], HC, DIM);
        k_wcvt<<<256, 256, 0, stream>>>(ff_W1 + (size_t)d * DIM * MLP_DIM, Wt[d][2], DIM, MLP_DIM);
        k_wcvt<<<256, 256, 0, stream>>>(ff_W2 + (size_t)d * MLP_DIM * DIM, Wt[d][3], MLP_DIM, DIM);
    }

    // CSR by dst (edges identical across layers)
    hipMemsetAsync(deg, 0, (size_t)(N_NODES + 1) * 4, stream);
    k_hist<<<(N_EDGES + 255) / 256, 256, 0, stream>>>(dstA, deg);
    k_scan<<<1, 1024, 0, stream>>>(deg, off, N_NODES);
    k_cursor<<<(N_NODES + 255) / 256, 256, 0, stream>>>(off, cur);
    k_fill<<<(N_EDGES + 255) / 256, 256, 0, stream>>>(dstA, cur, elist);

    const int MB = (N_NODES + 127) / 128;  // 313
    for (int d = 0; d < DEPTH_L; ++d) {
        // PreNorm + GAT
        k_ln<<<N_NODES / 4, 256, 0, stream>>>(x, ln1_g + d * DIM, ln1_b + d * DIM, h_ln, N_NODES);
        dim3 g1(MB, HC / 128);
        k_mm<0><<<g1, 256, 0, stream>>>((const short*)h_ln, (const short*)Wt[d][0],
                                        nullptr, nullptr, h2, N_NODES, HC, DIM);
        k_nodedots<<<N_NODES, 256, 0, stream>>>(
            h2, att_src + d * NHEAD * CHEAD, att_dst + d * NHEAD * CHEAD, asrc, adst);
        k_ae<<<1, 256, 0, stream>>>(edge_W + d * HC, att_edge + d * NHEAD * CHEAD, ae4);
        k_agg<<<N_NODES, 64, 0, stream>>>(off, elist, srcA, ea, asrc, adst, ae4, h2,
                                          gat_bias + d * HC, gbuf);
        dim3 g2(MB, 1);
        k_mm<2><<<g2, 256, 0, stream>>>((const short*)gbuf, (const short*)Wt[d][1],
                                        qf_b + d * DIM, x, x, N_NODES, DIM, HC);
        // PreNorm + FF
        k_ln<<<N_NODES / 4, 256, 0, stream>>>(x, ln2_g + d * DIM, ln2_b + d * DIM, h_ln, N_NODES);
        k_mm<1><<<g1, 256, 0, stream>>>((const short*)h_ln, (const short*)Wt[d][2],
                                        ff_b1 + d * MLP_DIM, nullptr, gbuf, N_NODES, MLP_DIM, DIM);
        k_mm<2><<<g2, 256, 0, stream>>>((const short*)gbuf, (const short*)Wt[d][3],
                                        ff_b2 + d * DIM, x, x, N_NODES, DIM, MLP_DIM);
    }
}